// Round 19
// baseline (187.666 us; speedup 1.0000x reference)
//
#include <hip/hip_runtime.h>
#include <stdint.h>

#define N_NODES 8192
#define IN_FEAT 512
#define OUT_FEAT 256
#define LOG2E 1.4426950408889634f

typedef __bf16 b16x8 __attribute__((ext_vector_type(8)));
typedef unsigned short u16x8v __attribute__((ext_vector_type(8)));
typedef float f32x4 __attribute__((ext_vector_type(4)));
typedef float f32x16 __attribute__((ext_vector_type(16)));

static __device__ __forceinline__ unsigned short f2bf(float f) {
    union { float f; uint32_t u; } v; v.f = f;
    uint32_t r = v.u + 0x7FFFu + ((v.u >> 16) & 1u);
    return (unsigned short)(r >> 16);
}

// K_pack: adj int32 [8192][8192] -> ROW-MAJOR bitmask (8 MB). Fully coalesced
// (~45us @ 86% HBM). First 512 blocks also do the W transpose (folded k0).
__global__ __launch_bounds__(256) void k_pack(const int* __restrict__ adj,
                                              unsigned char* __restrict__ bitsR,
                                              const float* __restrict__ W,
                                              unsigned short* __restrict__ Wt) {
    size_t t = (size_t)blockIdx.x * 256 + threadIdx.x;
    const int4* a4 = (const int4*)adj + t * 2;
    int4 x0 = a4[0];
    int4 x1 = a4[1];
    unsigned b = (unsigned)(x0.x != 0)
               | ((unsigned)(x0.y != 0) << 1)
               | ((unsigned)(x0.z != 0) << 2)
               | ((unsigned)(x0.w != 0) << 3)
               | ((unsigned)(x1.x != 0) << 4)
               | ((unsigned)(x1.y != 0) << 5)
               | ((unsigned)(x1.z != 0) << 6)
               | ((unsigned)(x1.w != 0) << 7);
    bitsR[t] = (unsigned char)b;
    if (blockIdx.x < 512) {
        int t0 = blockIdx.x * 256 + threadIdx.x;     // 0..131071
        int c = t0 & (OUT_FEAT - 1);
        int k = t0 >> 8;
        Wt[(size_t)c * IN_FEAT + k] = f2bf(W[(size_t)k * OUT_FEAT + c]);
    }
}

// K1: h = X @ W via bf16 MFMA (16x16x32 internally). Writes hTf32 in the
// B-fragment order of mfma_f32_32x32x16_bf16 (verified R16).
__global__ __launch_bounds__(256) void k1_hgemm(const float* __restrict__ input,
                                                const unsigned short* __restrict__ Wt,
                                                const float* __restrict__ a_vec,
                                                unsigned short* __restrict__ hTf32,
                                                float* __restrict__ s1_raw,
                                                float* __restrict__ s2_raw) {
    int tid = threadIdx.x;
    int lane = tid & 63;
    int c = lane & 15, g = lane >> 4;
    int r0 = blockIdx.x * 64 + (tid >> 6) * 16;
    f32x4 acc[16];
#pragma unroll
    for (int t = 0; t < 16; ++t) acc[t] = (f32x4){0.f, 0.f, 0.f, 0.f};
    const float* arow = input + (size_t)(r0 + c) * IN_FEAT;
#pragma unroll 1
    for (int kk = 0; kk < IN_FEAT / 32; ++kk) {
        int kb = kk * 32 + 8 * g;
        float4 x0 = *(const float4*)(arow + kb);
        float4 x1 = *(const float4*)(arow + kb + 4);
        u16x8v au;
        au[0] = f2bf(x0.x); au[1] = f2bf(x0.y); au[2] = f2bf(x0.z); au[3] = f2bf(x0.w);
        au[4] = f2bf(x1.x); au[5] = f2bf(x1.y); au[6] = f2bf(x1.z); au[7] = f2bf(x1.w);
        b16x8 af = __builtin_bit_cast(b16x8, au);
#pragma unroll
        for (int t = 0; t < 16; ++t) {
            b16x8 bf = __builtin_bit_cast(b16x8,
                *(const u16x8v*)(Wt + (size_t)(16 * t + c) * IN_FEAT + kb));
            acc[t] = __builtin_amdgcn_mfma_f32_16x16x32_bf16(af, bf, acc[t], 0, 0, 0);
        }
    }
    float a1v[16], a2v[16];
#pragma unroll
    for (int t = 0; t < 16; ++t) {
        a1v[t] = a_vec[16 * t + c];
        a2v[t] = a_vec[OUT_FEAT + 16 * t + c];
    }
#pragma unroll
    for (int r = 0; r < 4; ++r) {
        float s1p = 0.f, s2p = 0.f;
#pragma unroll
        for (int t = 0; t < 16; ++t) { s1p += acc[t][r] * a1v[t]; s2p += acc[t][r] * a2v[t]; }
#pragma unroll
        for (int m = 1; m <= 8; m <<= 1) { s1p += __shfl_xor(s1p, m); s2p += __shfl_xor(s2p, m); }
        if (c == 0) {
            int row = r0 + 4 * g + r;
            s1_raw[row] = s1p;
            s2_raw[row] = s2p;
        }
    }
    // store in 32x32 B-frag order
    int chunk16 = r0 >> 4;
    int lane_base = c + 32 * (g >> 1);
    int e0 = 4 * (g & 1);
#pragma unroll
    for (int t = 0; t < 16; ++t) {
        ushort4 pk;
        pk.x = f2bf(acc[t][0]); pk.y = f2bf(acc[t][1]);
        pk.z = f2bf(acc[t][2]); pk.w = f2bf(acc[t][3]);
        int lane_t = 16 * (t & 1) + lane_base;
        *(ushort4*)(hTf32 + ((size_t)(chunk16 * 8 + (t >> 1)) * 64 + lane_t) * 8 + e0) = pk;
    }
}

// K2: factored-exp constants.
__global__ __launch_bounds__(256) void k2_prep(const float* __restrict__ s1_raw,
                                               const float* __restrict__ s2_raw,
                                               float* __restrict__ e12,
                                               float2* __restrict__ row2) {
    __shared__ float red[256];
    int tid = threadIdx.x;
    float m = -3.0e38f;
    for (int j = tid; j < N_NODES; j += 256) m = fmaxf(m, s2_raw[j]);
    red[tid] = m;
    __syncthreads();
    for (int s = 128; s > 0; s >>= 1) {
        if (tid < s) red[tid] = fmaxf(red[tid], red[tid + s]);
        __syncthreads();
    }
    float M2 = red[0];
    int i = blockIdx.x * 256 + tid;
    float s1 = s1_raw[i];
    float u = s1 + M2;
    float mi = fmaxf(u, 0.2f * u);                 // per-row upper bound on e
    row2[i] = make_float2(__builtin_amdgcn_exp2f((s1 - mi) * LOG2E),
                          __builtin_amdgcn_exp2f((0.2f * s1 - mi) * LOG2E));
    float s2 = s2_raw[i];
    e12[2 * i]     = __builtin_amdgcn_exp2f(s2 * LOG2E);
    e12[2 * i + 1] = __builtin_amdgcn_exp2f(0.2f * s2 * LOG2E);
}

// K3 v18: FINE-WAVE af sharing — 8 waves x 1 col-tile, 6 waves/SIMD.
// Grid 1024 = 256 rowgroups (32 rows) x 4 jq. Block = 512 threads = 8 cq
// waves; wave cq owns col-tile cq (32 cols). acc = 1 x f32x16 = 16 VGPRs ->
// ~75 regs total -> fits 6 waves/SIMD (launch_bounds(512,6), 3 blocks/CU,
// 75% occupancy vs R17's 50%). Per int4-mask group (8 chunk16s): wave cq
// produces af for chunk 8k+cq ONLY (zero score duplication); barrier; all
// waves consume 8 slots (af ds_read + 1 b-frag + 1 MFMA); barrier.
__global__ __launch_bounds__(512, 6) void k3_flash(const uint32_t* __restrict__ maskR,
                                                   const unsigned short* __restrict__ hTf32,
                                                   const float* __restrict__ e12g,
                                                   const float2* __restrict__ row2,
                                                   float* __restrict__ pout,
                                                   float* __restrict__ rowpart) {
    __shared__ __align__(16) float le12[4096];               // 16 KB
    __shared__ __align__(16) unsigned short laf[8][512];     // 8 KB: af slots
    __shared__ float lsum[8][64];                            // 2 KB

    int tid = threadIdx.x;
    int cq = tid >> 6, lane = tid & 63;
    int lr = lane & 31, lo = lane >> 5;
    int jq = blockIdx.x & 3;
    int rg = blockIdx.x >> 2;
    int rowbase = rg * 32;

    // prologue: stage e12 quarter (8 floats/thread), one barrier
    *(float4*)&le12[tid * 8]     = *(const float4*)(e12g + (size_t)jq * 4096 + tid * 8);
    *(float4*)&le12[tid * 8 + 4] = *(const float4*)(e12g + (size_t)jq * 4096 + tid * 8 + 4);
    float2 rc = row2[rowbase + lr];
    float E1r = rc.x, E2r = rc.y;
    __syncthreads();

    // mask pointer: row lr, quarter jq (64 dwords), int4-grouped (8 chunk16s per int4)
    const int4* m4 = (const int4*)(maskR + (size_t)(rowbase + lr) * 256 + jq * 64);

    f32x16 acc0 = {0};
    float lacc = 0.f;
    int4 mq = m4[0];

#pragma unroll 1
    for (int kc8 = 0; kc8 < 16; ++kc8) {
        uint32_t md[4] = {(uint32_t)mq.x, (uint32_t)mq.y, (uint32_t)mq.z, (uint32_t)mq.w};

        // ---- produce af for chunk kc8*8 + cq (this wave's single slot) ----
        {
            int kc = kc8 * 8 + cq;
            float ev[16];
#pragma unroll
            for (int q = 0; q < 4; ++q)
                *(f32x4*)&ev[q * 4] = *(const f32x4*)&le12[(kc * 16 + 8 * lo) * 2 + q * 4];
            uint32_t mb = (md[cq >> 1] >> (16 * (cq & 1) + 8 * lo)) & 0xFFu;
            b16x8 af;
#pragma unroll
            for (int e = 0; e < 8; ++e) {
                float q0 = fmaxf(E1r * ev[2 * e], E2r * ev[2 * e + 1]);
                float p = (mb & (1u << e)) ? q0 : 0.f;
                lacc += p;
                af[e] = (__bf16)p;
            }
            *(u16x8v*)&laf[cq][lane * 8] = __builtin_bit_cast(u16x8v, af);
        }
        __syncthreads();

        // prefetch next group's mask (consumed after the next barrier)
        if (kc8 < 15) mq = m4[kc8 + 1];

        // ---- consume 8 slots with this wave's col-tile ----
        int gchunk0 = jq * 128 + kc8 * 8;
#pragma unroll
        for (int s = 0; s < 8; ++s) {
            const unsigned short* tb =
                hTf32 + ((size_t)((gchunk0 + s) * 8 + cq) * 64 + lane) * 8;
            b16x8 bf0 = __builtin_bit_cast(b16x8, *(const u16x8v*)(tb));
            b16x8 afs = __builtin_bit_cast(b16x8, *(const u16x8v*)&laf[s][lane * 8]);
            acc0 = __builtin_amdgcn_mfma_f32_32x32x16_bf16(afs, bf0, acc0, 0, 0, 0);
        }
        __syncthreads();                          // before next group's laf overwrite
    }

    // row sums: wave cq produced chunks ≡ cq (mod 8); merge via LDS
    lsum[cq][lane] = lacc;
    __syncthreads();
    if (cq == 0) {
        float l = 0.f;
#pragma unroll
        for (int s = 0; s < 8; ++s) l += lsum[s][lane];
        float ltot = l + __shfl_xor(l, 32);
        if (lo == 0) rowpart[jq * N_NODES + rowbase + lr] = ltot;
    }

    // C layout (32x32): col = lane&31, row = (reg&3) + 8*(reg>>2) + 4*(lane>>5)
#pragma unroll
    for (int reg = 0; reg < 16; ++reg) {
        int row = (reg & 3) + 8 * (reg >> 2) + 4 * lo;
        size_t base = ((size_t)jq * N_NODES + rowbase + row) * OUT_FEAT + cq * 32 + lr;
        pout[base] = acc0[reg];
    }
}

// K4: out = elu( (sum_q pout[q]) / (sum_q rowpart[q]) ).
__global__ __launch_bounds__(256) void k4_reduce(const float* __restrict__ pout,
                                                 const float* __restrict__ rowpart,
                                                 float* __restrict__ out) {
    int t = blockIdx.x * 256 + threadIdx.x;
    int row = t >> 8;
    float s = 0.f, l = 0.f;
#pragma unroll
    for (int q = 0; q < 4; ++q) {
        s += pout[(size_t)q * N_NODES * OUT_FEAT + t];
        l += rowpart[q * N_NODES + row];
    }
    float inv = (l > 0.f) ? 1.0f / l : 0.f;
    float x = s * inv;
    out[t] = (x > 0.f) ? x : (__builtin_amdgcn_exp2f(x * LOG2E) - 1.0f);
}

extern "C" void kernel_launch(void* const* d_in, const int* in_sizes, int n_in,
                              void* d_out, int out_size, void* d_ws, size_t ws_size,
                              hipStream_t stream) {
    const float* input = (const float*)d_in[0];
    const int* adj = (const int*)d_in[1];
    const float* W = (const float*)d_in[2];
    const float* a_vec = (const float*)d_in[3];
    float* out = (float*)d_out;

    char* ws = (char*)d_ws;
    unsigned short* Wt    = (unsigned short*)(ws);               // 256 KB
    unsigned short* hTf32 = (unsigned short*)(ws + 262144);      // 4 MB
    float*  e12     = (float*)(ws + 4456448);                    // 64 KB
    float2* row2    = (float2*)(ws + 4521984);                   // 64 KB
    float*  s1_raw  = (float*)(ws + 4587520);                    // 32 KB
    float*  s2_raw  = (float*)(ws + 4620288);                    // 32 KB
    unsigned char* bitsR = (unsigned char*)(ws + 4653056);       // 8 MB
    float*  rowpart = (float*)(ws + 13041664);                   // 128 KB
    float*  pout    = (float*)(ws + 13172736);                   // 32 MB

    hipLaunchKernelGGL(k_pack, dim3(32768), dim3(256), 0, stream, adj, bitsR, W, Wt);
    hipLaunchKernelGGL(k1_hgemm, dim3(N_NODES / 64), dim3(256), 0, stream,
                       input, Wt, a_vec, hTf32, s1_raw, s2_raw);
    hipLaunchKernelGGL(k2_prep, dim3(32), dim3(256), 0, stream, s1_raw, s2_raw, e12, row2);
    hipLaunchKernelGGL(k3_flash, dim3(1024), dim3(512), 0, stream,
                       (const uint32_t*)bitsR, hTf32, e12, row2, pout, rowpart);
    hipLaunchKernelGGL(k4_reduce, dim3(N_NODES * OUT_FEAT / 256), dim3(256), 0, stream,
                       pout, rowpart, out);
}

// Round 20
// 158.051 us; speedup vs baseline: 1.1874x; 1.1874x over previous
//
#include <hip/hip_runtime.h>
#include <stdint.h>

#define N_NODES 8192
#define IN_FEAT 512
#define OUT_FEAT 256
#define LOG2E 1.4426950408889634f

typedef __bf16 b16x8 __attribute__((ext_vector_type(8)));
typedef unsigned short u16x8v __attribute__((ext_vector_type(8)));
typedef float f32x4 __attribute__((ext_vector_type(4)));
typedef float f32x16 __attribute__((ext_vector_type(16)));

static __device__ __forceinline__ unsigned short f2bf(float f) {
    union { float f; uint32_t u; } v; v.f = f;
    uint32_t r = v.u + 0x7FFFu + ((v.u >> 16) & 1u);
    return (unsigned short)(r >> 16);
}

// K_pack: adj int32 [8192][8192] -> ROW-MAJOR bitmask (8 MB). Fully coalesced
// (~45us @ 86% HBM). First 512 blocks also do the W transpose (folded k0).
__global__ __launch_bounds__(256) void k_pack(const int* __restrict__ adj,
                                              unsigned char* __restrict__ bitsR,
                                              const float* __restrict__ W,
                                              unsigned short* __restrict__ Wt) {
    size_t t = (size_t)blockIdx.x * 256 + threadIdx.x;
    const int4* a4 = (const int4*)adj + t * 2;
    int4 x0 = a4[0];
    int4 x1 = a4[1];
    unsigned b = (unsigned)(x0.x != 0)
               | ((unsigned)(x0.y != 0) << 1)
               | ((unsigned)(x0.z != 0) << 2)
               | ((unsigned)(x0.w != 0) << 3)
               | ((unsigned)(x1.x != 0) << 4)
               | ((unsigned)(x1.y != 0) << 5)
               | ((unsigned)(x1.z != 0) << 6)
               | ((unsigned)(x1.w != 0) << 7);
    bitsR[t] = (unsigned char)b;
    if (blockIdx.x < 512) {
        int t0 = blockIdx.x * 256 + threadIdx.x;     // 0..131071
        int c = t0 & (OUT_FEAT - 1);
        int k = t0 >> 8;
        Wt[(size_t)c * IN_FEAT + k] = f2bf(W[(size_t)k * OUT_FEAT + c]);
    }
}

// K1: h = X @ W via bf16 MFMA (16x16x32 internally). Writes hTf32 in the
// B-fragment order of mfma_f32_32x32x16_bf16 (verified R16).
__global__ __launch_bounds__(256) void k1_hgemm(const float* __restrict__ input,
                                                const unsigned short* __restrict__ Wt,
                                                const float* __restrict__ a_vec,
                                                unsigned short* __restrict__ hTf32,
                                                float* __restrict__ s1_raw,
                                                float* __restrict__ s2_raw) {
    int tid = threadIdx.x;
    int lane = tid & 63;
    int c = lane & 15, g = lane >> 4;
    int r0 = blockIdx.x * 64 + (tid >> 6) * 16;
    f32x4 acc[16];
#pragma unroll
    for (int t = 0; t < 16; ++t) acc[t] = (f32x4){0.f, 0.f, 0.f, 0.f};
    const float* arow = input + (size_t)(r0 + c) * IN_FEAT;
#pragma unroll 1
    for (int kk = 0; kk < IN_FEAT / 32; ++kk) {
        int kb = kk * 32 + 8 * g;
        float4 x0 = *(const float4*)(arow + kb);
        float4 x1 = *(const float4*)(arow + kb + 4);
        u16x8v au;
        au[0] = f2bf(x0.x); au[1] = f2bf(x0.y); au[2] = f2bf(x0.z); au[3] = f2bf(x0.w);
        au[4] = f2bf(x1.x); au[5] = f2bf(x1.y); au[6] = f2bf(x1.z); au[7] = f2bf(x1.w);
        b16x8 af = __builtin_bit_cast(b16x8, au);
#pragma unroll
        for (int t = 0; t < 16; ++t) {
            b16x8 bf = __builtin_bit_cast(b16x8,
                *(const u16x8v*)(Wt + (size_t)(16 * t + c) * IN_FEAT + kb));
            acc[t] = __builtin_amdgcn_mfma_f32_16x16x32_bf16(af, bf, acc[t], 0, 0, 0);
        }
    }
    float a1v[16], a2v[16];
#pragma unroll
    for (int t = 0; t < 16; ++t) {
        a1v[t] = a_vec[16 * t + c];
        a2v[t] = a_vec[OUT_FEAT + 16 * t + c];
    }
#pragma unroll
    for (int r = 0; r < 4; ++r) {
        float s1p = 0.f, s2p = 0.f;
#pragma unroll
        for (int t = 0; t < 16; ++t) { s1p += acc[t][r] * a1v[t]; s2p += acc[t][r] * a2v[t]; }
#pragma unroll
        for (int m = 1; m <= 8; m <<= 1) { s1p += __shfl_xor(s1p, m); s2p += __shfl_xor(s2p, m); }
        if (c == 0) {
            int row = r0 + 4 * g + r;
            s1_raw[row] = s1p;
            s2_raw[row] = s2p;
        }
    }
    // store in 32x32 B-frag order
    int chunk16 = r0 >> 4;
    int lane_base = c + 32 * (g >> 1);
    int e0 = 4 * (g & 1);
#pragma unroll
    for (int t = 0; t < 16; ++t) {
        ushort4 pk;
        pk.x = f2bf(acc[t][0]); pk.y = f2bf(acc[t][1]);
        pk.z = f2bf(acc[t][2]); pk.w = f2bf(acc[t][3]);
        int lane_t = 16 * (t & 1) + lane_base;
        *(ushort4*)(hTf32 + ((size_t)(chunk16 * 8 + (t >> 1)) * 64 + lane_t) * 8 + e0) = pk;
    }
}

// K2: factored-exp constants.
__global__ __launch_bounds__(256) void k2_prep(const float* __restrict__ s1_raw,
                                               const float* __restrict__ s2_raw,
                                               float* __restrict__ e12,
                                               float2* __restrict__ row2) {
    __shared__ float red[256];
    int tid = threadIdx.x;
    float m = -3.0e38f;
    for (int j = tid; j < N_NODES; j += 256) m = fmaxf(m, s2_raw[j]);
    red[tid] = m;
    __syncthreads();
    for (int s = 128; s > 0; s >>= 1) {
        if (tid < s) red[tid] = fmaxf(red[tid], red[tid + s]);
        __syncthreads();
    }
    float M2 = red[0];
    int i = blockIdx.x * 256 + tid;
    float s1 = s1_raw[i];
    float u = s1 + M2;
    float mi = fmaxf(u, 0.2f * u);                 // per-row upper bound on e
    row2[i] = make_float2(__builtin_amdgcn_exp2f((s1 - mi) * LOG2E),
                          __builtin_amdgcn_exp2f((0.2f * s1 - mi) * LOG2E));
    float s2 = s2_raw[i];
    e12[2 * i]     = __builtin_amdgcn_exp2f(s2 * LOG2E);
    e12[2 * i + 1] = __builtin_amdgcn_exp2f(0.2f * s2 * LOG2E);
}

// K3 v19: R17/R18 shape (4 waves x 2 col-tiles, (256,4)) + DOUBLE-BUFFERED laf.
// Iteration k: consume group k from laf[k&1] WHILE producing group k+1 into
// laf[(k+1)&1] (independent streams, scheduler interleaves) — ONE barrier per
// group (16 total; R18 had 32 with serialized produce->consume phases).
__global__ __launch_bounds__(256, 4) void k3_flash(const uint32_t* __restrict__ maskR,
                                                   const unsigned short* __restrict__ hTf32,
                                                   const float* __restrict__ e12g,
                                                   const float2* __restrict__ row2,
                                                   float* __restrict__ pout,
                                                   float* __restrict__ rowpart) {
    __shared__ __align__(16) float le12[4096];               // 16 KB
    __shared__ __align__(16) unsigned short laf[2][8][512];  // 16 KB: dbuf af slots
    __shared__ float lsum[4][64];                            // 1 KB

    int tid = threadIdx.x;
    int cq = tid >> 6, lane = tid & 63;
    int lr = lane & 31, lo = lane >> 5;
    int jq = blockIdx.x & 3;
    int rg = blockIdx.x >> 2;
    int rowbase = rg * 32;

    // prologue: stage e12 quarter (16 floats/thread)
#pragma unroll
    for (int q = 0; q < 4; ++q) {
        *(float4*)&le12[tid * 16 + q * 4] =
            *(const float4*)(e12g + (size_t)jq * 4096 + tid * 16 + q * 4);
    }
    float2 rc = row2[rowbase + lr];
    float E1r = rc.x, E2r = rc.y;
    __syncthreads();

    // mask pointer: row lr, quarter jq (64 dwords), int4-grouped (8 chunk16s per int4)
    const int4* m4 = (const int4*)(maskR + (size_t)(rowbase + lr) * 256 + jq * 64);

    f32x16 acc0 = {0}, acc1 = {0};
    float lacc = 0.f;

#define PRODUCE_GROUP(BUF, KC8, MD)                                                      \
    {                                                                                    \
        _Pragma("unroll")                                                                \
        for (int hh = 0; hh < 2; ++hh) {                                                 \
            int sl = hh * 4 + cq;                                                        \
            int kc = (KC8) * 8 + sl;                                                     \
            float ev[16];                                                                \
            _Pragma("unroll")                                                            \
            for (int q = 0; q < 4; ++q)                                                  \
                *(f32x4*)&ev[q * 4] = *(const f32x4*)&le12[(kc * 16 + 8 * lo) * 2 + q * 4]; \
            uint32_t mb = ((MD)[sl >> 1] >> (16 * (sl & 1) + 8 * lo)) & 0xFFu;           \
            b16x8 af;                                                                    \
            _Pragma("unroll")                                                            \
            for (int e = 0; e < 8; ++e) {                                                \
                float q0 = fmaxf(E1r * ev[2 * e], E2r * ev[2 * e + 1]);                  \
                float p = (mb & (1u << e)) ? q0 : 0.f;                                   \
                lacc += p;                                                               \
                af[e] = (__bf16)p;                                                       \
            }                                                                            \
            *(u16x8v*)&laf[BUF][sl][lane * 8] = __builtin_bit_cast(u16x8v, af);          \
        }                                                                                \
    }

    {   // produce group 0 into laf[0]
        int4 mq0 = m4[0];
        uint32_t md[4] = {(uint32_t)mq0.x, (uint32_t)mq0.y, (uint32_t)mq0.z, (uint32_t)mq0.w};
        PRODUCE_GROUP(0, 0, md)
    }
    int4 mq = m4[1];          // mask for group 1 (next produce)
    __syncthreads();

#pragma unroll 1
    for (int kc8 = 0; kc8 < 16; ++kc8) {
        int cur = kc8 & 1;

        // produce group kc8+1 into laf[cur^1] (interleaves with consume below)
        if (kc8 < 15) {
            uint32_t md[4] = {(uint32_t)mq.x, (uint32_t)mq.y, (uint32_t)mq.z, (uint32_t)mq.w};
            PRODUCE_GROUP(cur ^ 1, kc8 + 1, md)
            if (kc8 < 14) mq = m4[kc8 + 2];
        }

        // consume 8 slots of group kc8 from laf[cur] with this wave's 2 col-tiles
        int gchunk0 = jq * 128 + kc8 * 8;
#pragma unroll
        for (int s = 0; s < 8; ++s) {
            const unsigned short* tb =
                hTf32 + ((size_t)((gchunk0 + s) * 8 + 2 * cq) * 64 + lane) * 8;
            b16x8 bf0 = __builtin_bit_cast(b16x8, *(const u16x8v*)(tb));
            b16x8 bf1 = __builtin_bit_cast(b16x8, *(const u16x8v*)(tb + 512));
            b16x8 afs = __builtin_bit_cast(b16x8, *(const u16x8v*)&laf[cur][s][lane * 8]);
            acc0 = __builtin_amdgcn_mfma_f32_32x32x16_bf16(afs, bf0, acc0, 0, 0, 0);
            acc1 = __builtin_amdgcn_mfma_f32_32x32x16_bf16(afs, bf1, acc1, 0, 0, 0);
        }
        __syncthreads();   // produce kc8+1 done & consume kc8 done; laf[cur] free
    }
#undef PRODUCE_GROUP

    // row sums: wave cq produced chunks ≡ {cq, cq+4} (mod 8); merge via LDS
    lsum[cq][lane] = lacc;
    __syncthreads();
    if (cq == 0) {
        float l = lsum[0][lane] + lsum[1][lane] + lsum[2][lane] + lsum[3][lane];
        float ltot = l + __shfl_xor(l, 32);
        if (lo == 0) rowpart[jq * N_NODES + rowbase + lr] = ltot;
    }

    // C layout (32x32): col = lane&31, row = (reg&3) + 8*(reg>>2) + 4*(lane>>5)
#pragma unroll
    for (int reg = 0; reg < 16; ++reg) {
        int row = (reg & 3) + 8 * (reg >> 2) + 4 * lo;
        size_t base = ((size_t)jq * N_NODES + rowbase + row) * OUT_FEAT + cq * 64 + lr;
        pout[base] = acc0[reg];
        pout[base + 32] = acc1[reg];
    }
}

// K4: out = elu( (sum_q pout[q]) / (sum_q rowpart[q]) ).
__global__ __launch_bounds__(256) void k4_reduce(const float* __restrict__ pout,
                                                 const float* __restrict__ rowpart,
                                                 float* __restrict__ out) {
    int t = blockIdx.x * 256 + threadIdx.x;
    int row = t >> 8;
    float s = 0.f, l = 0.f;
#pragma unroll
    for (int q = 0; q < 4; ++q) {
        s += pout[(size_t)q * N_NODES * OUT_FEAT + t];
        l += rowpart[q * N_NODES + row];
    }
    float inv = (l > 0.f) ? 1.0f / l : 0.f;
    float x = s * inv;
    out[t] = (x > 0.f) ? x : (__builtin_amdgcn_exp2f(x * LOG2E) - 1.0f);
}

extern "C" void kernel_launch(void* const* d_in, const int* in_sizes, int n_in,
                              void* d_out, int out_size, void* d_ws, size_t ws_size,
                              hipStream_t stream) {
    const float* input = (const float*)d_in[0];
    const int* adj = (const int*)d_in[1];
    const float* W = (const float*)d_in[2];
    const float* a_vec = (const float*)d_in[3];
    float* out = (float*)d_out;

    char* ws = (char*)d_ws;
    unsigned short* Wt    = (unsigned short*)(ws);               // 256 KB
    unsigned short* hTf32 = (unsigned short*)(ws + 262144);      // 4 MB
    float*  e12     = (float*)(ws + 4456448);                    // 64 KB
    float2* row2    = (float2*)(ws + 4521984);                   // 64 KB
    float*  s1_raw  = (float*)(ws + 4587520);                    // 32 KB
    float*  s2_raw  = (float*)(ws + 4620288);                    // 32 KB
    unsigned char* bitsR = (unsigned char*)(ws + 4653056);       // 8 MB
    float*  rowpart = (float*)(ws + 13041664);                   // 128 KB
    float*  pout    = (float*)(ws + 13172736);                   // 32 MB

    hipLaunchKernelGGL(k_pack, dim3(32768), dim3(256), 0, stream, adj, bitsR, W, Wt);
    hipLaunchKernelGGL(k1_hgemm, dim3(N_NODES / 64), dim3(256), 0, stream,
                       input, Wt, a_vec, hTf32, s1_raw, s2_raw);
    hipLaunchKernelGGL(k2_prep, dim3(32), dim3(256), 0, stream, s1_raw, s2_raw, e12, row2);
    hipLaunchKernelGGL(k3_flash, dim3(1024), dim3(256), 0, stream,
                       (const uint32_t*)bitsR, hTf32, e12, row2, pout, rowpart);
    hipLaunchKernelGGL(k4_reduce, dim3(N_NODES * OUT_FEAT / 256), dim3(256), 0, stream,
                       pout, rowpart, out);
}

// Round 21
// 157.688 us; speedup vs baseline: 1.1901x; 1.0023x over previous
//
#include <hip/hip_runtime.h>
#include <stdint.h>

#define N_NODES 8192
#define IN_FEAT 512
#define OUT_FEAT 256
#define LOG2E 1.4426950408889634f

typedef __bf16 b16x8 __attribute__((ext_vector_type(8)));
typedef unsigned short u16x8v __attribute__((ext_vector_type(8)));
typedef float f32x4 __attribute__((ext_vector_type(4)));
typedef float f32x16 __attribute__((ext_vector_type(16)));

static __device__ __forceinline__ unsigned short f2bf(float f) {
    union { float f; uint32_t u; } v; v.f = f;
    uint32_t r = v.u + 0x7FFFu + ((v.u >> 16) & 1u);
    return (unsigned short)(r >> 16);
}

// K_pack: adj int32 [8192][8192] -> ROW-MAJOR bitmask (8 MB). Fully coalesced
// (~45us @ 86% HBM). First 512 blocks also do the W transpose (folded k0).
__global__ __launch_bounds__(256) void k_pack(const int* __restrict__ adj,
                                              unsigned char* __restrict__ bitsR,
                                              const float* __restrict__ W,
                                              unsigned short* __restrict__ Wt) {
    size_t t = (size_t)blockIdx.x * 256 + threadIdx.x;
    const int4* a4 = (const int4*)adj + t * 2;
    int4 x0 = a4[0];
    int4 x1 = a4[1];
    unsigned b = (unsigned)(x0.x != 0)
               | ((unsigned)(x0.y != 0) << 1)
               | ((unsigned)(x0.z != 0) << 2)
               | ((unsigned)(x0.w != 0) << 3)
               | ((unsigned)(x1.x != 0) << 4)
               | ((unsigned)(x1.y != 0) << 5)
               | ((unsigned)(x1.z != 0) << 6)
               | ((unsigned)(x1.w != 0) << 7);
    bitsR[t] = (unsigned char)b;
    if (blockIdx.x < 512) {
        int t0 = blockIdx.x * 256 + threadIdx.x;     // 0..131071
        int c = t0 & (OUT_FEAT - 1);
        int k = t0 >> 8;
        Wt[(size_t)c * IN_FEAT + k] = f2bf(W[(size_t)k * OUT_FEAT + c]);
    }
}

// K1: h = X @ W via bf16 MFMA (16x16x32 internally). Writes hTf32 in the
// B-fragment order of mfma_f32_32x32x16_bf16 (verified R16).
__global__ __launch_bounds__(256) void k1_hgemm(const float* __restrict__ input,
                                                const unsigned short* __restrict__ Wt,
                                                const float* __restrict__ a_vec,
                                                unsigned short* __restrict__ hTf32,
                                                float* __restrict__ s1_raw,
                                                float* __restrict__ s2_raw) {
    int tid = threadIdx.x;
    int lane = tid & 63;
    int c = lane & 15, g = lane >> 4;
    int r0 = blockIdx.x * 64 + (tid >> 6) * 16;
    f32x4 acc[16];
#pragma unroll
    for (int t = 0; t < 16; ++t) acc[t] = (f32x4){0.f, 0.f, 0.f, 0.f};
    const float* arow = input + (size_t)(r0 + c) * IN_FEAT;
#pragma unroll 1
    for (int kk = 0; kk < IN_FEAT / 32; ++kk) {
        int kb = kk * 32 + 8 * g;
        float4 x0 = *(const float4*)(arow + kb);
        float4 x1 = *(const float4*)(arow + kb + 4);
        u16x8v au;
        au[0] = f2bf(x0.x); au[1] = f2bf(x0.y); au[2] = f2bf(x0.z); au[3] = f2bf(x0.w);
        au[4] = f2bf(x1.x); au[5] = f2bf(x1.y); au[6] = f2bf(x1.z); au[7] = f2bf(x1.w);
        b16x8 af = __builtin_bit_cast(b16x8, au);
#pragma unroll
        for (int t = 0; t < 16; ++t) {
            b16x8 bf = __builtin_bit_cast(b16x8,
                *(const u16x8v*)(Wt + (size_t)(16 * t + c) * IN_FEAT + kb));
            acc[t] = __builtin_amdgcn_mfma_f32_16x16x32_bf16(af, bf, acc[t], 0, 0, 0);
        }
    }
    float a1v[16], a2v[16];
#pragma unroll
    for (int t = 0; t < 16; ++t) {
        a1v[t] = a_vec[16 * t + c];
        a2v[t] = a_vec[OUT_FEAT + 16 * t + c];
    }
#pragma unroll
    for (int r = 0; r < 4; ++r) {
        float s1p = 0.f, s2p = 0.f;
#pragma unroll
        for (int t = 0; t < 16; ++t) { s1p += acc[t][r] * a1v[t]; s2p += acc[t][r] * a2v[t]; }
#pragma unroll
        for (int m = 1; m <= 8; m <<= 1) { s1p += __shfl_xor(s1p, m); s2p += __shfl_xor(s2p, m); }
        if (c == 0) {
            int row = r0 + 4 * g + r;
            s1_raw[row] = s1p;
            s2_raw[row] = s2p;
        }
    }
    // store in 32x32 B-frag order
    int chunk16 = r0 >> 4;
    int lane_base = c + 32 * (g >> 1);
    int e0 = 4 * (g & 1);
#pragma unroll
    for (int t = 0; t < 16; ++t) {
        ushort4 pk;
        pk.x = f2bf(acc[t][0]); pk.y = f2bf(acc[t][1]);
        pk.z = f2bf(acc[t][2]); pk.w = f2bf(acc[t][3]);
        int lane_t = 16 * (t & 1) + lane_base;
        *(ushort4*)(hTf32 + ((size_t)(chunk16 * 8 + (t >> 1)) * 64 + lane_t) * 8 + e0) = pk;
    }
}

// K2: factored-exp constants.
__global__ __launch_bounds__(256) void k2_prep(const float* __restrict__ s1_raw,
                                               const float* __restrict__ s2_raw,
                                               float* __restrict__ e12,
                                               float2* __restrict__ row2) {
    __shared__ float red[256];
    int tid = threadIdx.x;
    float m = -3.0e38f;
    for (int j = tid; j < N_NODES; j += 256) m = fmaxf(m, s2_raw[j]);
    red[tid] = m;
    __syncthreads();
    for (int s = 128; s > 0; s >>= 1) {
        if (tid < s) red[tid] = fmaxf(red[tid], red[tid + s]);
        __syncthreads();
    }
    float M2 = red[0];
    int i = blockIdx.x * 256 + tid;
    float s1 = s1_raw[i];
    float u = s1 + M2;
    float mi = fmaxf(u, 0.2f * u);                 // per-row upper bound on e
    row2[i] = make_float2(__builtin_amdgcn_exp2f((s1 - mi) * LOG2E),
                          __builtin_amdgcn_exp2f((0.2f * s1 - mi) * LOG2E));
    float s2 = s2_raw[i];
    e12[2 * i]     = __builtin_amdgcn_exp2f(s2 * LOG2E);
    e12[2 * i + 1] = __builtin_amdgcn_exp2f(0.2f * s2 * LOG2E);
}

// K3 v20: v19 (dbuf laf, 16 barriers) + T5 s_setprio around the consume
// MFMA cluster. Roles per iteration: produce (VALU+LDS) vs consume (MFMA+L1);
// setprio(1) keeps the MFMA/L1 stream fed while co-resident waves run their
// produce bursts at low priority. Math unchanged -> absmax must be identical.
__global__ __launch_bounds__(256, 4) void k3_flash(const uint32_t* __restrict__ maskR,
                                                   const unsigned short* __restrict__ hTf32,
                                                   const float* __restrict__ e12g,
                                                   const float2* __restrict__ row2,
                                                   float* __restrict__ pout,
                                                   float* __restrict__ rowpart) {
    __shared__ __align__(16) float le12[4096];               // 16 KB
    __shared__ __align__(16) unsigned short laf[2][8][512];  // 16 KB: dbuf af slots
    __shared__ float lsum[4][64];                            // 1 KB

    int tid = threadIdx.x;
    int cq = tid >> 6, lane = tid & 63;
    int lr = lane & 31, lo = lane >> 5;
    int jq = blockIdx.x & 3;
    int rg = blockIdx.x >> 2;
    int rowbase = rg * 32;

    // prologue: stage e12 quarter (16 floats/thread)
#pragma unroll
    for (int q = 0; q < 4; ++q) {
        *(float4*)&le12[tid * 16 + q * 4] =
            *(const float4*)(e12g + (size_t)jq * 4096 + tid * 16 + q * 4);
    }
    float2 rc = row2[rowbase + lr];
    float E1r = rc.x, E2r = rc.y;
    __syncthreads();

    // mask pointer: row lr, quarter jq (64 dwords), int4-grouped (8 chunk16s per int4)
    const int4* m4 = (const int4*)(maskR + (size_t)(rowbase + lr) * 256 + jq * 64);

    f32x16 acc0 = {0}, acc1 = {0};
    float lacc = 0.f;

#define PRODUCE_GROUP(BUF, KC8, MD)                                                      \
    {                                                                                    \
        _Pragma("unroll")                                                                \
        for (int hh = 0; hh < 2; ++hh) {                                                 \
            int sl = hh * 4 + cq;                                                        \
            int kc = (KC8) * 8 + sl;                                                     \
            float ev[16];                                                                \
            _Pragma("unroll")                                                            \
            for (int q = 0; q < 4; ++q)                                                  \
                *(f32x4*)&ev[q * 4] = *(const f32x4*)&le12[(kc * 16 + 8 * lo) * 2 + q * 4]; \
            uint32_t mb = ((MD)[sl >> 1] >> (16 * (sl & 1) + 8 * lo)) & 0xFFu;           \
            b16x8 af;                                                                    \
            _Pragma("unroll")                                                            \
            for (int e = 0; e < 8; ++e) {                                                \
                float q0 = fmaxf(E1r * ev[2 * e], E2r * ev[2 * e + 1]);                  \
                float p = (mb & (1u << e)) ? q0 : 0.f;                                   \
                lacc += p;                                                               \
                af[e] = (__bf16)p;                                                       \
            }                                                                            \
            *(u16x8v*)&laf[BUF][sl][lane * 8] = __builtin_bit_cast(u16x8v, af);          \
        }                                                                                \
    }

    {   // produce group 0 into laf[0]
        int4 mq0 = m4[0];
        uint32_t md[4] = {(uint32_t)mq0.x, (uint32_t)mq0.y, (uint32_t)mq0.z, (uint32_t)mq0.w};
        PRODUCE_GROUP(0, 0, md)
    }
    int4 mq = m4[1];          // mask for group 1 (next produce)
    __syncthreads();

#pragma unroll 1
    for (int kc8 = 0; kc8 < 16; ++kc8) {
        int cur = kc8 & 1;

        // produce group kc8+1 into laf[cur^1] (interleaves with consume below)
        if (kc8 < 15) {
            uint32_t md[4] = {(uint32_t)mq.x, (uint32_t)mq.y, (uint32_t)mq.z, (uint32_t)mq.w};
            PRODUCE_GROUP(cur ^ 1, kc8 + 1, md)
            if (kc8 < 14) mq = m4[kc8 + 2];
        }

        // consume 8 slots of group kc8 from laf[cur] with this wave's 2 col-tiles
        int gchunk0 = jq * 128 + kc8 * 8;
        __builtin_amdgcn_s_setprio(1);
#pragma unroll
        for (int s = 0; s < 8; ++s) {
            const unsigned short* tb =
                hTf32 + ((size_t)((gchunk0 + s) * 8 + 2 * cq) * 64 + lane) * 8;
            b16x8 bf0 = __builtin_bit_cast(b16x8, *(const u16x8v*)(tb));
            b16x8 bf1 = __builtin_bit_cast(b16x8, *(const u16x8v*)(tb + 512));
            b16x8 afs = __builtin_bit_cast(b16x8, *(const u16x8v*)&laf[cur][s][lane * 8]);
            acc0 = __builtin_amdgcn_mfma_f32_32x32x16_bf16(afs, bf0, acc0, 0, 0, 0);
            acc1 = __builtin_amdgcn_mfma_f32_32x32x16_bf16(afs, bf1, acc1, 0, 0, 0);
        }
        __builtin_amdgcn_s_setprio(0);
        __syncthreads();   // produce kc8+1 done & consume kc8 done; laf[cur] free
    }
#undef PRODUCE_GROUP

    // row sums: wave cq produced chunks ≡ {cq, cq+4} (mod 8); merge via LDS
    lsum[cq][lane] = lacc;
    __syncthreads();
    if (cq == 0) {
        float l = lsum[0][lane] + lsum[1][lane] + lsum[2][lane] + lsum[3][lane];
        float ltot = l + __shfl_xor(l, 32);
        if (lo == 0) rowpart[jq * N_NODES + rowbase + lr] = ltot;
    }

    // C layout (32x32): col = lane&31, row = (reg&3) + 8*(reg>>2) + 4*(lane>>5)
#pragma unroll
    for (int reg = 0; reg < 16; ++reg) {
        int row = (reg & 3) + 8 * (reg >> 2) + 4 * lo;
        size_t base = ((size_t)jq * N_NODES + rowbase + row) * OUT_FEAT + cq * 64 + lr;
        pout[base] = acc0[reg];
        pout[base + 32] = acc1[reg];
    }
}

// K4: out = elu( (sum_q pout[q]) / (sum_q rowpart[q]) ).
__global__ __launch_bounds__(256) void k4_reduce(const float* __restrict__ pout,
                                                 const float* __restrict__ rowpart,
                                                 float* __restrict__ out) {
    int t = blockIdx.x * 256 + threadIdx.x;
    int row = t >> 8;
    float s = 0.f, l = 0.f;
#pragma unroll
    for (int q = 0; q < 4; ++q) {
        s += pout[(size_t)q * N_NODES * OUT_FEAT + t];
        l += rowpart[q * N_NODES + row];
    }
    float inv = (l > 0.f) ? 1.0f / l : 0.f;
    float x = s * inv;
    out[t] = (x > 0.f) ? x : (__builtin_amdgcn_exp2f(x * LOG2E) - 1.0f);
}

extern "C" void kernel_launch(void* const* d_in, const int* in_sizes, int n_in,
                              void* d_out, int out_size, void* d_ws, size_t ws_size,
                              hipStream_t stream) {
    const float* input = (const float*)d_in[0];
    const int* adj = (const int*)d_in[1];
    const float* W = (const float*)d_in[2];
    const float* a_vec = (const float*)d_in[3];
    float* out = (float*)d_out;

    char* ws = (char*)d_ws;
    unsigned short* Wt    = (unsigned short*)(ws);               // 256 KB
    unsigned short* hTf32 = (unsigned short*)(ws + 262144);      // 4 MB
    float*  e12     = (float*)(ws + 4456448);                    // 64 KB
    float2* row2    = (float2*)(ws + 4521984);                   // 64 KB
    float*  s1_raw  = (float*)(ws + 4587520);                    // 32 KB
    float*  s2_raw  = (float*)(ws + 4620288);                    // 32 KB
    unsigned char* bitsR = (unsigned char*)(ws + 4653056);       // 8 MB
    float*  rowpart = (float*)(ws + 13041664);                   // 128 KB
    float*  pout    = (float*)(ws + 13172736);                   // 32 MB

    hipLaunchKernelGGL(k_pack, dim3(32768), dim3(256), 0, stream, adj, bitsR, W, Wt);
    hipLaunchKernelGGL(k1_hgemm, dim3(N_NODES / 64), dim3(256), 0, stream,
                       input, Wt, a_vec, hTf32, s1_raw, s2_raw);
    hipLaunchKernelGGL(k2_prep, dim3(32), dim3(256), 0, stream, s1_raw, s2_raw, e12, row2);
    hipLaunchKernelGGL(k3_flash, dim3(1024), dim3(256), 0, stream,
                       (const uint32_t*)bitsR, hTf32, e12, row2, pout, rowpart);
    hipLaunchKernelGGL(k4_reduce, dim3(N_NODES * OUT_FEAT / 256), dim3(256), 0, stream,
                       pout, rowpart, out);
}

// Round 22
// 155.038 us; speedup vs baseline: 1.2105x; 1.0171x over previous
//
#include <hip/hip_runtime.h>
#include <stdint.h>

#define N_NODES 8192
#define IN_FEAT 512
#define OUT_FEAT 256
#define LOG2E 1.4426950408889634f

typedef __bf16 b16x8 __attribute__((ext_vector_type(8)));
typedef unsigned short u16x8v __attribute__((ext_vector_type(8)));
typedef float f32x4 __attribute__((ext_vector_type(4)));
typedef float f32x16 __attribute__((ext_vector_type(16)));

static __device__ __forceinline__ unsigned short f2bf(float f) {
    union { float f; uint32_t u; } v; v.f = f;
    uint32_t r = v.u + 0x7FFFu + ((v.u >> 16) & 1u);
    return (unsigned short)(r >> 16);
}
static __device__ __forceinline__ float bf2f(unsigned short s) {
    union { uint32_t u; float f; } v; v.u = ((uint32_t)s) << 16;
    return v.f;
}

// K0: Wt[c][k] = bf16(W[k][c])  (256 x 512)
__global__ __launch_bounds__(256) void k0_transpose_w(const float* __restrict__ W,
                                                      unsigned short* __restrict__ Wt) {
    int tid = blockIdx.x * 256 + threadIdx.x;
    int c = tid & (OUT_FEAT - 1);
    int k = tid >> 8;
    Wt[(size_t)c * IN_FEAT + k] = f2bf(W[(size_t)k * OUT_FEAT + c]);
}

// K1: h = X @ W via bf16 MFMA (16x16x32 internally). Writes hTf32 in the
// B-fragment order of mfma_f32_32x32x16_bf16 (verified R16).
__global__ __launch_bounds__(256) void k1_hgemm(const float* __restrict__ input,
                                                const unsigned short* __restrict__ Wt,
                                                const float* __restrict__ a_vec,
                                                unsigned short* __restrict__ hTf32,
                                                float* __restrict__ s1_raw,
                                                float* __restrict__ s2_raw) {
    int tid = threadIdx.x;
    int lane = tid & 63;
    int c = lane & 15, g = lane >> 4;
    int r0 = blockIdx.x * 64 + (tid >> 6) * 16;
    f32x4 acc[16];
#pragma unroll
    for (int t = 0; t < 16; ++t) acc[t] = (f32x4){0.f, 0.f, 0.f, 0.f};
    const float* arow = input + (size_t)(r0 + c) * IN_FEAT;
#pragma unroll 1
    for (int kk = 0; kk < IN_FEAT / 32; ++kk) {
        int kb = kk * 32 + 8 * g;
        float4 x0 = *(const float4*)(arow + kb);
        float4 x1 = *(const float4*)(arow + kb + 4);
        u16x8v au;
        au[0] = f2bf(x0.x); au[1] = f2bf(x0.y); au[2] = f2bf(x0.z); au[3] = f2bf(x0.w);
        au[4] = f2bf(x1.x); au[5] = f2bf(x1.y); au[6] = f2bf(x1.z); au[7] = f2bf(x1.w);
        b16x8 af = __builtin_bit_cast(b16x8, au);
#pragma unroll
        for (int t = 0; t < 16; ++t) {
            b16x8 bf = __builtin_bit_cast(b16x8,
                *(const u16x8v*)(Wt + (size_t)(16 * t + c) * IN_FEAT + kb));
            acc[t] = __builtin_amdgcn_mfma_f32_16x16x32_bf16(af, bf, acc[t], 0, 0, 0);
        }
    }
    float a1v[16], a2v[16];
#pragma unroll
    for (int t = 0; t < 16; ++t) {
        a1v[t] = a_vec[16 * t + c];
        a2v[t] = a_vec[OUT_FEAT + 16 * t + c];
    }
#pragma unroll
    for (int r = 0; r < 4; ++r) {
        float s1p = 0.f, s2p = 0.f;
#pragma unroll
        for (int t = 0; t < 16; ++t) { s1p += acc[t][r] * a1v[t]; s2p += acc[t][r] * a2v[t]; }
#pragma unroll
        for (int m = 1; m <= 8; m <<= 1) { s1p += __shfl_xor(s1p, m); s2p += __shfl_xor(s2p, m); }
        if (c == 0) {
            int row = r0 + 4 * g + r;
            s1_raw[row] = s1p;
            s2_raw[row] = s2p;
        }
    }
    // store in 32x32 B-frag order
    int chunk16 = r0 >> 4;
    int lane_base = c + 32 * (g >> 1);
    int e0 = 4 * (g & 1);
#pragma unroll
    for (int t = 0; t < 16; ++t) {
        ushort4 pk;
        pk.x = f2bf(acc[t][0]); pk.y = f2bf(acc[t][1]);
        pk.z = f2bf(acc[t][2]); pk.w = f2bf(acc[t][3]);
        int lane_t = 16 * (t & 1) + lane_base;
        *(ushort4*)(hTf32 + ((size_t)(chunk16 * 8 + (t >> 1)) * 64 + lane_t) * 8 + e0) = pk;
    }
}

// K2: factored-exp constants.
__global__ __launch_bounds__(256) void k2_prep(const float* __restrict__ s1_raw,
                                               const float* __restrict__ s2_raw,
                                               float* __restrict__ e12,
                                               float2* __restrict__ row2) {
    __shared__ float red[256];
    int tid = threadIdx.x;
    float m = -3.0e38f;
    for (int j = tid; j < N_NODES; j += 256) m = fmaxf(m, s2_raw[j]);
    red[tid] = m;
    __syncthreads();
    for (int s = 128; s > 0; s >>= 1) {
        if (tid < s) red[tid] = fmaxf(red[tid], red[tid + s]);
        __syncthreads();
    }
    float M2 = red[0];
    int i = blockIdx.x * 256 + tid;
    float s1 = s1_raw[i];
    float u = s1 + M2;
    float mi = fmaxf(u, 0.2f * u);                 // per-row upper bound on e
    row2[i] = make_float2(__builtin_amdgcn_exp2f((s1 - mi) * LOG2E),
                          __builtin_amdgcn_exp2f((0.2f * s1 - mi) * LOG2E));
    float s2 = s2_raw[i];
    e12[2 * i]     = __builtin_amdgcn_exp2f(s2 * LOG2E);
    e12[2 * i + 1] = __builtin_amdgcn_exp2f(0.2f * s2 * LOG2E);
}

// K3 v21: FUSED pack + flash-GAT. Grid 2048 = 256 rowgroups (32 rows) x 8 jq
// (j-eighths, 1024 js). Block = 256 = 4 cq waves, wave owns 2 col-tiles.
// PROLOGUE bulk-stages the block's raw adj slab (32 rows x 1024 js = 128 KB,
// fully coalesced 16-iter burst) and packs it into a 4.6 KB LDS bitmask —
// k_pack kernel deleted; adj read exactly once grid-wide. 2x oversubscription
// (8 blocks/CU of work, 4 resident) overlaps late blocks' staging with early
// blocks' compute. Main loop = R18 shape (produce 2 af slots -> barrier ->
// consume 8 -> barrier), masks from LDS. pout partials in BF16 (8 slots,
// 32 MB total; bitsR's 8 MB freed).
__global__ __launch_bounds__(256, 4) void k3_flash(const int* __restrict__ adj,
                                                   const unsigned short* __restrict__ hTf32,
                                                   const float* __restrict__ e12g,
                                                   const float2* __restrict__ row2,
                                                   unsigned short* __restrict__ poutb,
                                                   float* __restrict__ rowpart) {
    __shared__ __align__(16) float le12[2048];               // 8 KB (eighth)
    __shared__ __align__(16) unsigned short laf[8][512];     // 8 KB af slots
    __shared__ __align__(16) uint32_t lmask[32 * 36];        // 4.6 KB, row pitch 36 dw
    __shared__ float lsum[4][64];                            // 1 KB

    int tid = threadIdx.x;
    int cq = tid >> 6, lane = tid & 63;
    int lr = lane & 31, lo = lane >> 5;
    int jq = blockIdx.x & 7;
    int rg = blockIdx.x >> 3;
    int rowbase = rg * 32;

    // ---- prologue: stage e12 eighth (8 floats/thread) ----
    *(float4*)&le12[tid * 8]     = *(const float4*)(e12g + (size_t)jq * 2048 + tid * 8);
    *(float4*)&le12[tid * 8 + 4] = *(const float4*)(e12g + (size_t)jq * 2048 + tid * 8 + 4);

    // ---- prologue: bulk-stage + pack adj slab (32 rows x 1024 js) ----
    // mask byte b (0..4095): row = b>>7, byte-in-row = b&127 (8 js per byte).
#pragma unroll 4
    for (int it = 0; it < 16; ++it) {
        int b = it * 256 + tid;
        int row = b >> 7;
        int bir = b & 127;
        const int4* src = (const int4*)(adj + (size_t)(rowbase + row) * N_NODES
                                        + jq * 1024 + bir * 8);
        int4 v0 = src[0];
        int4 v1 = src[1];
        unsigned pb = (unsigned)(v0.x != 0) | ((unsigned)(v0.y != 0) << 1)
                    | ((unsigned)(v0.z != 0) << 2) | ((unsigned)(v0.w != 0) << 3)
                    | ((unsigned)(v1.x != 0) << 4) | ((unsigned)(v1.y != 0) << 5)
                    | ((unsigned)(v1.z != 0) << 6) | ((unsigned)(v1.w != 0) << 7);
        ((unsigned char*)lmask)[row * 144 + bir] = (unsigned char)pb;
    }
    float2 rc = row2[rowbase + lr];
    float E1r = rc.x, E2r = rc.y;
    __syncthreads();

    f32x16 acc0 = {0}, acc1 = {0};
    float lacc = 0.f;

#pragma unroll 1
    for (int kc8 = 0; kc8 < 8; ++kc8) {
        // masks for this group: 8 chunk16s = 4 dwords of row lr
        int4 mq = *(const int4*)((const char*)lmask + lr * 144 + kc8 * 16);
        uint32_t md[4] = {(uint32_t)mq.x, (uint32_t)mq.y, (uint32_t)mq.z, (uint32_t)mq.w};

        // ---- produce 2 af slots (chunks kc8*8+cq, kc8*8+4+cq) ----
#pragma unroll
        for (int hh = 0; hh < 2; ++hh) {
            int sl = hh * 4 + cq;
            int kc = kc8 * 8 + sl;                 // chunk16 in eighth (0..63)
            float ev[16];
#pragma unroll
            for (int q = 0; q < 4; ++q)
                *(f32x4*)&ev[q * 4] = *(const f32x4*)&le12[(kc * 16 + 8 * lo) * 2 + q * 4];
            uint32_t mb = (md[sl >> 1] >> (16 * (sl & 1) + 8 * lo)) & 0xFFu;
            b16x8 af;
#pragma unroll
            for (int e = 0; e < 8; ++e) {
                float q0 = fmaxf(E1r * ev[2 * e], E2r * ev[2 * e + 1]);
                float p = (mb & (1u << e)) ? q0 : 0.f;
                lacc += p;
                af[e] = (__bf16)p;
            }
            *(u16x8v*)&laf[sl][lane * 8] = __builtin_bit_cast(u16x8v, af);
        }
        __syncthreads();

        // ---- consume 8 slots with this wave's 2 col-tiles ----
        int gchunk0 = jq * 64 + kc8 * 8;           // global chunk16
#pragma unroll
        for (int s = 0; s < 8; ++s) {
            const unsigned short* tb =
                hTf32 + ((size_t)((gchunk0 + s) * 8 + 2 * cq) * 64 + lane) * 8;
            b16x8 bf0 = __builtin_bit_cast(b16x8, *(const u16x8v*)(tb));
            b16x8 bf1 = __builtin_bit_cast(b16x8, *(const u16x8v*)(tb + 512));
            b16x8 afs = __builtin_bit_cast(b16x8, *(const u16x8v*)&laf[s][lane * 8]);
            acc0 = __builtin_amdgcn_mfma_f32_32x32x16_bf16(afs, bf0, acc0, 0, 0, 0);
            acc1 = __builtin_amdgcn_mfma_f32_32x32x16_bf16(afs, bf1, acc1, 0, 0, 0);
        }
        __syncthreads();                           // before next group's laf overwrite
    }

    // row sums: wave cq produced chunks ≡ {cq, cq+4} (mod 8); merge via LDS
    lsum[cq][lane] = lacc;
    __syncthreads();
    if (cq == 0) {
        float l = lsum[0][lane] + lsum[1][lane] + lsum[2][lane] + lsum[3][lane];
        float ltot = l + __shfl_xor(l, 32);
        if (lo == 0) rowpart[jq * N_NODES + rowbase + lr] = ltot;
    }

    // C layout (32x32): col = lane&31, row = (reg&3) + 8*(reg>>2) + 4*(lane>>5)
#pragma unroll
    for (int reg = 0; reg < 16; ++reg) {
        int row = (reg & 3) + 8 * (reg >> 2) + 4 * lo;
        size_t base = ((size_t)jq * N_NODES + rowbase + row) * OUT_FEAT + cq * 64 + lr;
        poutb[base] = f2bf(acc0[reg]);
        poutb[base + 32] = f2bf(acc1[reg]);
    }
}

// K4: out = elu( (sum_q bf2f(poutb[q])) / (sum_q rowpart[q]) ), 8 quarters.
__global__ __launch_bounds__(256) void k4_reduce(const unsigned short* __restrict__ poutb,
                                                 const float* __restrict__ rowpart,
                                                 float* __restrict__ out) {
    int t = blockIdx.x * 256 + threadIdx.x;
    int row = t >> 8;
    float s = 0.f, l = 0.f;
#pragma unroll
    for (int q = 0; q < 8; ++q) {
        s += bf2f(poutb[(size_t)q * N_NODES * OUT_FEAT + t]);
        l += rowpart[q * N_NODES + row];
    }
    float inv = (l > 0.f) ? 1.0f / l : 0.f;
    float x = s * inv;
    out[t] = (x > 0.f) ? x : (__builtin_amdgcn_exp2f(x * LOG2E) - 1.0f);
}

extern "C" void kernel_launch(void* const* d_in, const int* in_sizes, int n_in,
                              void* d_out, int out_size, void* d_ws, size_t ws_size,
                              hipStream_t stream) {
    const float* input = (const float*)d_in[0];
    const int* adj = (const int*)d_in[1];
    const float* W = (const float*)d_in[2];
    const float* a_vec = (const float*)d_in[3];
    float* out = (float*)d_out;

    char* ws = (char*)d_ws;
    unsigned short* Wt    = (unsigned short*)(ws);               // 256 KB
    unsigned short* hTf32 = (unsigned short*)(ws + 262144);      // 4 MB
    float*  e12     = (float*)(ws + 4456448);                    // 64 KB
    float2* row2    = (float2*)(ws + 4521984);                   // 64 KB
    float*  s1_raw  = (float*)(ws + 4587520);                    // 32 KB
    float*  s2_raw  = (float*)(ws + 4620288);                    // 32 KB
    float*  rowpart = (float*)(ws + 4653056);                    // 256 KB
    unsigned short* poutb = (unsigned short*)(ws + 4915200);     // 32 MB

    hipLaunchKernelGGL(k0_transpose_w, dim3(512), dim3(256), 0, stream, W, Wt);
    hipLaunchKernelGGL(k1_hgemm, dim3(N_NODES / 64), dim3(256), 0, stream,
                       input, Wt, a_vec, hTf32, s1_raw, s2_raw);
    hipLaunchKernelGGL(k2_prep, dim3(32), dim3(256), 0, stream, s1_raw, s2_raw, e12, row2);
    hipLaunchKernelGGL(k3_flash, dim3(2048), dim3(256), 0, stream,
                       adj, hTf32, e12, row2, poutb, rowpart);
    hipLaunchKernelGGL(k4_reduce, dim3(N_NODES * OUT_FEAT / 256), dim3(256), 0, stream,
                       poutb, rowpart, out);
}

// Round 23
// 150.912 us; speedup vs baseline: 1.2436x; 1.0273x over previous
//
#include <hip/hip_runtime.h>
#include <stdint.h>

#define N_NODES 8192
#define IN_FEAT 512
#define OUT_FEAT 256
#define LOG2E 1.4426950408889634f

typedef __bf16 b16x8 __attribute__((ext_vector_type(8)));
typedef unsigned short u16x8v __attribute__((ext_vector_type(8)));
typedef float f32x4 __attribute__((ext_vector_type(4)));
typedef float f32x16 __attribute__((ext_vector_type(16)));

static __device__ __forceinline__ unsigned short f2bf(float f) {
    union { float f; uint32_t u; } v; v.f = f;
    uint32_t r = v.u + 0x7FFFu + ((v.u >> 16) & 1u);
    return (unsigned short)(r >> 16);
}
static __device__ __forceinline__ float bf2f(unsigned short s) {
    union { uint32_t u; float f; } v; v.u = ((uint32_t)s) << 16;
    return v.f;
}

// K0: Wt[c][k] = bf16(W[k][c])  (256 x 512)
__global__ __launch_bounds__(256) void k0_transpose_w(const float* __restrict__ W,
                                                      unsigned short* __restrict__ Wt) {
    int tid = blockIdx.x * 256 + threadIdx.x;
    int c = tid & (OUT_FEAT - 1);
    int k = tid >> 8;
    Wt[(size_t)c * IN_FEAT + k] = f2bf(W[(size_t)k * OUT_FEAT + c]);
}

// K1: h = X @ W via bf16 MFMA (16x16x32 internally). Writes hTf32 in the
// B-fragment order of mfma_f32_32x32x16_bf16 (verified R16).
__global__ __launch_bounds__(256) void k1_hgemm(const float* __restrict__ input,
                                                const unsigned short* __restrict__ Wt,
                                                const float* __restrict__ a_vec,
                                                unsigned short* __restrict__ hTf32,
                                                float* __restrict__ s1_raw,
                                                float* __restrict__ s2_raw) {
    int tid = threadIdx.x;
    int lane = tid & 63;
    int c = lane & 15, g = lane >> 4;
    int r0 = blockIdx.x * 64 + (tid >> 6) * 16;
    f32x4 acc[16];
#pragma unroll
    for (int t = 0; t < 16; ++t) acc[t] = (f32x4){0.f, 0.f, 0.f, 0.f};
    const float* arow = input + (size_t)(r0 + c) * IN_FEAT;
#pragma unroll 1
    for (int kk = 0; kk < IN_FEAT / 32; ++kk) {
        int kb = kk * 32 + 8 * g;
        float4 x0 = *(const float4*)(arow + kb);
        float4 x1 = *(const float4*)(arow + kb + 4);
        u16x8v au;
        au[0] = f2bf(x0.x); au[1] = f2bf(x0.y); au[2] = f2bf(x0.z); au[3] = f2bf(x0.w);
        au[4] = f2bf(x1.x); au[5] = f2bf(x1.y); au[6] = f2bf(x1.z); au[7] = f2bf(x1.w);
        b16x8 af = __builtin_bit_cast(b16x8, au);
#pragma unroll
        for (int t = 0; t < 16; ++t) {
            b16x8 bf = __builtin_bit_cast(b16x8,
                *(const u16x8v*)(Wt + (size_t)(16 * t + c) * IN_FEAT + kb));
            acc[t] = __builtin_amdgcn_mfma_f32_16x16x32_bf16(af, bf, acc[t], 0, 0, 0);
        }
    }
    float a1v[16], a2v[16];
#pragma unroll
    for (int t = 0; t < 16; ++t) {
        a1v[t] = a_vec[16 * t + c];
        a2v[t] = a_vec[OUT_FEAT + 16 * t + c];
    }
#pragma unroll
    for (int r = 0; r < 4; ++r) {
        float s1p = 0.f, s2p = 0.f;
#pragma unroll
        for (int t = 0; t < 16; ++t) { s1p += acc[t][r] * a1v[t]; s2p += acc[t][r] * a2v[t]; }
#pragma unroll
        for (int m = 1; m <= 8; m <<= 1) { s1p += __shfl_xor(s1p, m); s2p += __shfl_xor(s2p, m); }
        if (c == 0) {
            int row = r0 + 4 * g + r;
            s1_raw[row] = s1p;
            s2_raw[row] = s2p;
        }
    }
    // store in 32x32 B-frag order
    int chunk16 = r0 >> 4;
    int lane_base = c + 32 * (g >> 1);
    int e0 = 4 * (g & 1);
#pragma unroll
    for (int t = 0; t < 16; ++t) {
        ushort4 pk;
        pk.x = f2bf(acc[t][0]); pk.y = f2bf(acc[t][1]);
        pk.z = f2bf(acc[t][2]); pk.w = f2bf(acc[t][3]);
        int lane_t = 16 * (t & 1) + lane_base;
        *(ushort4*)(hTf32 + ((size_t)(chunk16 * 8 + (t >> 1)) * 64 + lane_t) * 8 + e0) = pk;
    }
}

// K2: factored-exp constants.
__global__ __launch_bounds__(256) void k2_prep(const float* __restrict__ s1_raw,
                                               const float* __restrict__ s2_raw,
                                               float* __restrict__ e12,
                                               float2* __restrict__ row2) {
    __shared__ float red[256];
    int tid = threadIdx.x;
    float m = -3.0e38f;
    for (int j = tid; j < N_NODES; j += 256) m = fmaxf(m, s2_raw[j]);
    red[tid] = m;
    __syncthreads();
    for (int s = 128; s > 0; s >>= 1) {
        if (tid < s) red[tid] = fmaxf(red[tid], red[tid + s]);
        __syncthreads();
    }
    float M2 = red[0];
    int i = blockIdx.x * 256 + tid;
    float s1 = s1_raw[i];
    float u = s1 + M2;
    float mi = fmaxf(u, 0.2f * u);                 // per-row upper bound on e
    row2[i] = make_float2(__builtin_amdgcn_exp2f((s1 - mi) * LOG2E),
                          __builtin_amdgcn_exp2f((0.2f * s1 - mi) * LOG2E));
    float s2 = s2_raw[i];
    e12[2 * i]     = __builtin_amdgcn_exp2f(s2 * LOG2E);
    e12[2 * i + 1] = __builtin_amdgcn_exp2f(0.2f * s2 * LOG2E);
}

// K3 v22: fused pack+flash-GAT with IN-LOOP depth-1 adj register pipeline.
// Grid 2048 = 256 rowgroups (32 rows) x 8 jq (j-eighths). Block = 256 = 4 cq
// waves, wave owns 2 col-tiles. Iteration kc8: [issue adj loads for group
// kc8+1 -> regs] [produce 2 af slots from lmask[cur]] [barrier] [consume 8
// slots: b-frags + 16 MFMA] [pack regs -> lmask[cur^1]] [barrier].
// Pack's counted-vmcnt lands ~1 full phase after issue; no global_load_lds
// in flight (the R6-R9 drain trap doesn't apply). adj read once grid-wide,
// streamed across all iterations -> overlaps compute. jq = blockIdx&7 = XCD:
// each XCD caches one 512KB hT eighth + its adj stripe.
__global__ __launch_bounds__(256, 4) void k3_flash(const int* __restrict__ adj,
                                                   const unsigned short* __restrict__ hTf32,
                                                   const float* __restrict__ e12g,
                                                   const float2* __restrict__ row2,
                                                   unsigned short* __restrict__ poutb,
                                                   float* __restrict__ rowpart) {
    __shared__ __align__(16) float le12[2048];               // 8 KB (eighth)
    __shared__ __align__(16) unsigned short laf[8][512];     // 8 KB af slots
    __shared__ __align__(16) uint32_t lmask[2][32][4];       // 1 KB dbuf masks
    __shared__ float lsum[4][64];                            // 1 KB

    int tid = threadIdx.x;
    int cq = tid >> 6, lane = tid & 63;
    int lr = lane & 31, lo = lane >> 5;
    int jq = blockIdx.x & 7;
    int rg = blockIdx.x >> 3;
    int rowbase = rg * 32;

    // adj staging mapping: thread t -> row t>>3, j-block (t&7)*16 within group
    int srow = tid >> 3;
    int sjb = tid & 7;
    const int* adjbase = adj + (size_t)(rowbase + srow) * N_NODES + jq * 1024 + sjb * 16;

    // ---- prologue: stage e12 eighth (8 floats/thread) ----
    *(float4*)&le12[tid * 8]     = *(const float4*)(e12g + (size_t)jq * 2048 + tid * 8);
    *(float4*)&le12[tid * 8 + 4] = *(const float4*)(e12g + (size_t)jq * 2048 + tid * 8 + 4);

#define PACK16(BUF, V)                                                                   \
    {                                                                                    \
        unsigned pb = 0;                                                                 \
        _Pragma("unroll")                                                                \
        for (int k = 0; k < 4; ++k) {                                                    \
            pb |= ((unsigned)((V)[k].x != 0) << (4 * k))                                 \
                | ((unsigned)((V)[k].y != 0) << (4 * k + 1))                             \
                | ((unsigned)((V)[k].z != 0) << (4 * k + 2))                             \
                | ((unsigned)((V)[k].w != 0) << (4 * k + 3));                            \
        }                                                                                \
        *(unsigned short*)((char*)&lmask[BUF][srow][0] + sjb * 2) = (unsigned short)pb;  \
    }

    {   // synchronous pack of group 0 into lmask[0]
        int4 v[4];
#pragma unroll
        for (int k = 0; k < 4; ++k) v[k] = *(const int4*)(adjbase + 4 * k);
        PACK16(0, v)
    }
    float2 rc = row2[rowbase + lr];
    float E1r = rc.x, E2r = rc.y;
    __syncthreads();

    f32x16 acc0 = {0}, acc1 = {0};
    float lacc = 0.f;

#pragma unroll 1
    for (int kc8 = 0; kc8 < 8; ++kc8) {
        int cur = kc8 & 1;

        // A) issue adj loads for group kc8+1 (consumed at pack, ~1 phase later)
        int4 v[4];
        if (kc8 < 7) {
#pragma unroll
            for (int k = 0; k < 4; ++k)
                v[k] = *(const int4*)(adjbase + (kc8 + 1) * 128 + 4 * k);
        }

        // B) produce 2 af slots (chunks kc8*8+cq, kc8*8+4+cq) from lmask[cur]
        int4 mq = *(const int4*)&lmask[cur][lr][0];
        uint32_t md[4] = {(uint32_t)mq.x, (uint32_t)mq.y, (uint32_t)mq.z, (uint32_t)mq.w};
#pragma unroll
        for (int hh = 0; hh < 2; ++hh) {
            int sl = hh * 4 + cq;
            int kc = kc8 * 8 + sl;                 // chunk16 in eighth (0..63)
            float ev[16];
#pragma unroll
            for (int q = 0; q < 4; ++q)
                *(f32x4*)&ev[q * 4] = *(const f32x4*)&le12[(kc * 16 + 8 * lo) * 2 + q * 4];
            uint32_t mb = (md[sl >> 1] >> (16 * (sl & 1) + 8 * lo)) & 0xFFu;
            b16x8 af;
#pragma unroll
            for (int e = 0; e < 8; ++e) {
                float q0 = fmaxf(E1r * ev[2 * e], E2r * ev[2 * e + 1]);
                float p = (mb & (1u << e)) ? q0 : 0.f;
                lacc += p;
                af[e] = (__bf16)p;
            }
            *(u16x8v*)&laf[sl][lane * 8] = __builtin_bit_cast(u16x8v, af);
        }
        __syncthreads();

        // C) consume 8 slots with this wave's 2 col-tiles
        int gchunk0 = jq * 64 + kc8 * 8;           // global chunk16
#pragma unroll
        for (int s = 0; s < 8; ++s) {
            const unsigned short* tb =
                hTf32 + ((size_t)((gchunk0 + s) * 8 + 2 * cq) * 64 + lane) * 8;
            b16x8 bf0 = __builtin_bit_cast(b16x8, *(const u16x8v*)(tb));
            b16x8 bf1 = __builtin_bit_cast(b16x8, *(const u16x8v*)(tb + 512));
            b16x8 afs = __builtin_bit_cast(b16x8, *(const u16x8v*)&laf[s][lane * 8]);
            acc0 = __builtin_amdgcn_mfma_f32_32x32x16_bf16(afs, bf0, acc0, 0, 0, 0);
            acc1 = __builtin_amdgcn_mfma_f32_32x32x16_bf16(afs, bf1, acc1, 0, 0, 0);
        }

        // D) pack group kc8+1 -> lmask[cur^1] (regs waited here, counted vmcnt)
        if (kc8 < 7) PACK16(cur ^ 1, v)
        __syncthreads();                           // laf + lmask[cur^1] ready
    }
#undef PACK16

    // row sums: wave cq produced chunks ≡ {cq, cq+4} (mod 8); merge via LDS
    lsum[cq][lane] = lacc;
    __syncthreads();
    if (cq == 0) {
        float l = lsum[0][lane] + lsum[1][lane] + lsum[2][lane] + lsum[3][lane];
        float ltot = l + __shfl_xor(l, 32);
        if (lo == 0) rowpart[jq * N_NODES + rowbase + lr] = ltot;
    }

    // C layout (32x32): col = lane&31, row = (reg&3) + 8*(reg>>2) + 4*(lane>>5)
#pragma unroll
    for (int reg = 0; reg < 16; ++reg) {
        int row = (reg & 3) + 8 * (reg >> 2) + 4 * lo;
        size_t base = ((size_t)jq * N_NODES + rowbase + row) * OUT_FEAT + cq * 64 + lr;
        poutb[base] = f2bf(acc0[reg]);
        poutb[base + 32] = f2bf(acc1[reg]);
    }
}

// K4: out = elu( (sum_q bf2f(poutb[q])) / (sum_q rowpart[q]) ), 8 eighths.
__global__ __launch_bounds__(256) void k4_reduce(const unsigned short* __restrict__ poutb,
                                                 const float* __restrict__ rowpart,
                                                 float* __restrict__ out) {
    int t = blockIdx.x * 256 + threadIdx.x;
    int row = t >> 8;
    float s = 0.f, l = 0.f;
#pragma unroll
    for (int q = 0; q < 8; ++q) {
        s += bf2f(poutb[(size_t)q * N_NODES * OUT_FEAT + t]);
        l += rowpart[q * N_NODES + row];
    }
    float inv = (l > 0.f) ? 1.0f / l : 0.f;
    float x = s * inv;
    out[t] = (x > 0.f) ? x : (__builtin_amdgcn_exp2f(x * LOG2E) - 1.0f);
}

extern "C" void kernel_launch(void* const* d_in, const int* in_sizes, int n_in,
                              void* d_out, int out_size, void* d_ws, size_t ws_size,
                              hipStream_t stream) {
    const float* input = (const float*)d_in[0];
    const int* adj = (const int*)d_in[1];
    const float* W = (const float*)d_in[2];
    const float* a_vec = (const float*)d_in[3];
    float* out = (float*)d_out;

    char* ws = (char*)d_ws;
    unsigned short* Wt    = (unsigned short*)(ws);               // 256 KB
    unsigned short* hTf32 = (unsigned short*)(ws + 262144);      // 4 MB
    float*  e12     = (float*)(ws + 4456448);                    // 64 KB
    float2* row2    = (float2*)(ws + 4521984);                   // 64 KB
    float*  s1_raw  = (float*)(ws + 4587520);                    // 32 KB
    float*  s2_raw  = (float*)(ws + 4620288);                    // 32 KB
    float*  rowpart = (float*)(ws + 4653056);                    // 256 KB
    unsigned short* poutb = (unsigned short*)(ws + 4915200);     // 32 MB

    hipLaunchKernelGGL(k0_transpose_w, dim3(512), dim3(256), 0, stream, W, Wt);
    hipLaunchKernelGGL(k1_hgemm, dim3(N_NODES / 64), dim3(256), 0, stream,
                       input, Wt, a_vec, hTf32, s1_raw, s2_raw);
    hipLaunchKernelGGL(k2_prep, dim3(32), dim3(256), 0, stream, s1_raw, s2_raw, e12, row2);
    hipLaunchKernelGGL(k3_flash, dim3(2048), dim3(256), 0, stream,
                       adj, hTf32, e12, row2, poutb, rowpart);
    hipLaunchKernelGGL(k4_reduce, dim3(N_NODES * OUT_FEAT / 256), dim3(256), 0, stream,
                       poutb, rowpart, out);
}